// Round 4
// baseline (2493.408 us; speedup 1.0000x reference)
//
#include <hip/hip_runtime.h>
#include <stdint.h>

constexpr int kS = 512;   // sequence length
constexpr int kB = 32;    // batch (only element 0 decoded)
constexpr int kH = 512;   // hidden
constexpr int kV = 64;    // tags

// ---------------------------------------------------------------------------
// ws layout (floats):
//   X   [512][512]     @ 0        (262144)
//   H0  [2][512][512]  @ 262144   (524288)   sentinel-initialized
//   H1  [2][512][512]  @ 786432   (524288)   sentinel-initialized
//   LOG [512][64]      @ 1310720  (32768)
// ---------------------------------------------------------------------------

__device__ __forceinline__ float fast_sigmoid(float x) {
  return __builtin_amdgcn_rcpf(1.0f + __expf(-x));
}
__device__ __forceinline__ float fast_tanh(float x) {
  return 1.0f - 2.0f * __builtin_amdgcn_rcpf(1.0f + __expf(2.0f * x));
}
__device__ __forceinline__ float bcast(float v, int k) {
  return __uint_as_float(__builtin_amdgcn_readlane(__float_as_uint(v), k));
}

__global__ __launch_bounds__(128) void k_embed(const int* __restrict__ src,
                                               const float* __restrict__ emb,
                                               float* __restrict__ X) {
  const int t = blockIdx.x;
  const int s = src[t * kB];  // batch 0 token
  const float4* e = (const float4*)(emb + (size_t)s * 512);
  float4* x = (float4*)(X + (size_t)t * 512);
  x[threadIdx.x] = e[threadIdx.x];
}

// Fused recurrence: 64 blocks (dir = bx&1, wg = bx>>1 of 32), 512 threads.
// wg owns h[wg*16..+16) -> 64 gate rows; lane l of each wave owns gate row l;
// wave wv owns k-slice [wv*64,+64) of Whh and [wv*KZ/8,+KZ/8) of Wih, weights
// in registers. Handoff protocol (round-4): per-lane atomics DO NOT coalesce,
// so (a) producers publish 8x atomic-u64 (paired via shuffle) instead of 16x
// u32 to the same line; (b) consumers spin with only 4 probe lanes (one per
// 64B line) + s_sleep backoff, then ONE 64-lane atomic read with a ballot
// recheck for partial-line stragglers; (c) the first probe issues BEFORE the
// z-matvec so its RTT hides under ~200+ VALU instructions.
template <int KZ>
__global__ __launch_bounds__(512, 1) void k_rec(
    const float* __restrict__ Z0,   // layer0: X; layer1: H0 fwd
    const float* __restrict__ Z1,   // layer1: H0 bwd (unused for KZ==512)
    const float* __restrict__ Wih,  // [2][2048][KZ]
    const float* __restrict__ Whh,  // [2][2048][512]
    const float* __restrict__ bih,  // [2][2048]
    const float* __restrict__ bhh,  // [2][2048]
    float* __restrict__ Hout) {     // [2][512][512], sentinel-initialized
  constexpr int ZPW = KZ / 8;       // z k-slice per wave (64 or 128)
  __shared__ float part[64 * 10];   // [row][wave], stride 10 (8B-aligned)
  const int bx = blockIdx.x;
  const int dir = bx & 1, wg = bx >> 1;
  const int tid = threadIdx.x;
  const int wv = tid >> 6, l = tid & 63;
  const float* WihB = Wih + (size_t)dir * 2048 * KZ;
  const float* WhhB = Whh + (size_t)dir * 2048 * 512;
  float* Hb = Hout + (size_t)dir * kS * kH;
  const int grow = (l >> 4) * 512 + wg * 16 + (l & 15);

  // --- one-time weight loads into registers ---
  float ww[64];
  {
    const float* wp = WhhB + (size_t)grow * 512 + wv * 64;
#pragma unroll
    for (int i = 0; i < 64; i += 4) {
      const float4 v = *(const float4*)(wp + i);
      ww[i] = v.x; ww[i + 1] = v.y; ww[i + 2] = v.z; ww[i + 3] = v.w;
    }
  }
  float zw[ZPW];
  {
    const float* zp = WihB + (size_t)grow * KZ + wv * ZPW;
#pragma unroll
    for (int i = 0; i < ZPW; i += 4) {
      const float4 v = *(const float4*)(zp + i);
      zw[i] = v.x; zw[i + 1] = v.y; zw[i + 2] = v.z; zw[i + 3] = v.w;
    }
  }
  float bias = 0.0f;
  if (wv == 0) bias = bih[dir * 2048 + grow] + bhh[dir * 2048 + grow];
  float cstate = 0.0f;  // live in wave 0, lanes < 16

  const float* zbase = (KZ == 512) ? Z0 : ((wv < 4) ? Z0 : Z1);
  const int zoff = (KZ == 512) ? tid : ((wv & 3) * 128 + l);

  const int t0 = dir ? (kS - 1) : 0;
  float zc0 = zbase[(size_t)t0 * 512 + zoff];
  float zc1 = (KZ == 1024) ? zbase[(size_t)t0 * 512 + zoff + 64] : 0.0f;

  for (int s = 0; s < kS; s++) {
    const int t = dir ? (kS - 1 - s) : s;
    int tn = dir ? (t - 1) : (t + 1);
    if (tn < 0) tn = 0;
    if (tn > kS - 1) tn = kS - 1;
    const int tp = dir ? (t + 1) : (t - 1);
    const unsigned* hrow =
        (const unsigned*)(Hb + (size_t)(s > 0 ? tp : t) * kH);

    // --- issue first probe BEFORE the z-matvec: RTT hides under it ---
    unsigned probe = 0;
    if (s > 0 && l < 4) {
      probe = __hip_atomic_load(hrow + wv * 64 + l * 16, __ATOMIC_RELAXED,
                                __HIP_MEMORY_SCOPE_AGENT);
    }

    // next-step z prefetch (independent global loads)
    const float zn0 = zbase[(size_t)tn * 512 + zoff];
    const float zn1 = (KZ == 1024) ? zbase[(size_t)tn * 512 + zoff + 64] : 0.0f;

    // --- input-gate matvec: independent of h ---
    float a0 = 0.f, a1 = 0.f, a2 = 0.f, a3 = 0.f;
#pragma unroll
    for (int k = 0; k < 64; k += 4) {
      a0 += zw[k + 0] * bcast(zc0, k + 0);
      a1 += zw[k + 1] * bcast(zc0, k + 1);
      a2 += zw[k + 2] * bcast(zc0, k + 2);
      a3 += zw[k + 3] * bcast(zc0, k + 3);
    }
    if (KZ == 1024) {
#pragma unroll
      for (int k = 0; k < 64; k += 4) {
        a0 += zw[64 + k + 0] * bcast(zc1, k + 0);
        a1 += zw[64 + k + 1] * bcast(zc1, k + 1);
        a2 += zw[64 + k + 2] * bcast(zc1, k + 2);
        a3 += zw[64 + k + 3] * bcast(zc1, k + 3);
      }
    }

    // --- finish poll: 4-lane probe spin, then one bulk read + recheck ---
    float hreg = 0.0f;
    if (s > 0) {
      if (l < 4) {
        const unsigned* pp = hrow + wv * 64 + l * 16;
        while (probe == 0xFFFFFFFFu) {
          __builtin_amdgcn_s_sleep(1);
          probe = __hip_atomic_load(pp, __ATOMIC_RELAXED,
                                    __HIP_MEMORY_SCOPE_AGENT);
        }
      }
      const unsigned* hp = hrow + tid;
      unsigned u = __hip_atomic_load(hp, __ATOMIC_RELAXED,
                                     __HIP_MEMORY_SCOPE_AGENT);
      while (__ballot(u == 0xFFFFFFFFu)) {  // rare: partial-line straggler
        __builtin_amdgcn_s_sleep(1);
        u = __hip_atomic_load(hp, __ATOMIC_RELAXED, __HIP_MEMORY_SCOPE_AGENT);
      }
      hreg = __uint_as_float(u);
    }

    // --- recurrent matvec ---
#pragma unroll
    for (int k = 0; k < 64; k += 4) {
      a0 += ww[k + 0] * bcast(hreg, k + 0);
      a1 += ww[k + 1] * bcast(hreg, k + 1);
      a2 += ww[k + 2] * bcast(hreg, k + 2);
      a3 += ww[k + 3] * bcast(hreg, k + 3);
    }
    part[l * 10 + wv] = (a0 + a1) + (a2 + a3);
    __syncthreads();
    // waves 1..7 fall through to next step immediately; wave 0 does the cell.
    if (wv == 0) {
      float ssum = bias;
#pragma unroll
      for (int w = 0; w < 8; w++) ssum += part[l * 10 + w];
      const float sf = __shfl(ssum, (l + 16) & 63);
      const float sg = __shfl(ssum, (l + 32) & 63);
      const float so = __shfl(ssum, (l + 48) & 63);
      float hval = 0.0f;
      if (l < 16) {
        const float ig = fast_sigmoid(ssum);
        const float fg = fast_sigmoid(sf);
        const float og = fast_sigmoid(so);
        cstate = fg * cstate + ig * fast_tanh(sg);
        hval = og * fast_tanh(cstate);
      }
      // pack pairs -> 8 atomic u64 stores (halve same-line atomic ops)
      const float lo = __shfl(hval, 2 * l);
      const float hi = __shfl(hval, 2 * l + 1);
      if (l < 8) {
        const unsigned long long pk =
            (unsigned long long)__float_as_uint(lo) |
            ((unsigned long long)__float_as_uint(hi) << 32);
        __hip_atomic_store(
            (unsigned long long*)(Hb + (size_t)t * kH + wg * 16) + l, pk,
            __ATOMIC_RELAXED, __HIP_MEMORY_SCOPE_AGENT);
      }
    }
    zc0 = zn0;
    zc1 = zn1;
  }
}

__global__ __launch_bounds__(256) void k_logits(const float* __restrict__ H1,
                                                const float* __restrict__ Wout,
                                                const float* __restrict__ bout,
                                                float* __restrict__ LOG) {
  __shared__ float hl[1024];
  const int t = blockIdx.x;
  const int tid = threadIdx.x;
  float4* hl4 = (float4*)hl;
  if (tid < 128)
    hl4[tid] = ((const float4*)(H1 + (size_t)t * kH))[tid];
  else
    hl4[tid] = ((const float4*)(H1 + (size_t)(kS + t) * kH))[tid - 128];
  __syncthreads();
  const int v = tid >> 2, q = tid & 3;
  const float4* w4 = (const float4*)(Wout + (size_t)v * 1024);
  float4 a = {0, 0, 0, 0};
#pragma unroll 8
  for (int j = 0; j < 64; j++) {
    const int idx = j * 4 + q;
    const float4 w = w4[idx];
    const float4 x = hl4[idx];
    a.x += w.x * x.x; a.y += w.y * x.y; a.z += w.z * x.z; a.w += w.w * x.w;
  }
  float acc = (a.x + a.y) + (a.z + a.w);
  acc += __shfl_xor(acc, 1);
  acc += __shfl_xor(acc, 2);
  if (q == 0) LOG[(size_t)t * kV + v] = acc + bout[v];
}

__global__ __launch_bounds__(256) void k_viterbi(const float* __restrict__ LOG,
                                                 const float* __restrict__ trans,
                                                 int* __restrict__ out) {
  __shared__ float delta[64];
  __shared__ float redS[4 * 64];
  __shared__ int redA[4 * 64];
  __shared__ unsigned char bp[511 * 64];
  const int tid = threadIdx.x;
  const int c = tid & 63, q = tid >> 6;
  if (tid < 64) delta[tid] = LOG[tid];
  __syncthreads();
  for (int t = 1; t < kS; t++) {
    float best = -1e30f;
    int bi = 0;
#pragma unroll 4
    for (int pp = 0; pp < 16; pp++) {
      const int p = q * 16 + pp;
      const float sc = delta[p] + trans[p * 64 + c];
      if (sc > best) { best = sc; bi = p; }  // strict > == first-max (numpy)
    }
    redS[q * 64 + c] = best;
    redA[q * 64 + c] = bi;
    __syncthreads();
    if (tid < 64) {
      float b = redS[c];
      int a = redA[c];
      for (int qq = 1; qq < 4; qq++) {
        const float v2 = redS[qq * 64 + c];
        if (v2 > b) { b = v2; a = redA[qq * 64 + c]; }
      }
      bp[(t - 1) * 64 + c] = (unsigned char)a;
      delta[c] = b + LOG[t * 64 + c];
    }
    __syncthreads();
  }
  if (tid == 0) {
    float b = delta[0];
    int a = 0;
    for (int i = 1; i < 64; i++)
      if (delta[i] > b) { b = delta[i]; a = i; }
    int idx = a;
    out[kS - 1] = idx;
    for (int t = kS - 2; t >= 0; t--) {
      idx = bp[t * 64 + idx];
      out[t] = idx;
    }
  }
}

extern "C" void kernel_launch(void* const* d_in, const int* in_sizes, int n_in,
                              void* d_out, int out_size, void* d_ws,
                              size_t ws_size, hipStream_t stream) {
  (void)in_sizes; (void)n_in; (void)out_size; (void)ws_size;
  const int* source  = (const int*)d_in[0];
  const float* emb   = (const float*)d_in[2];
  const float* Wih0  = (const float*)d_in[3];
  const float* Whh0  = (const float*)d_in[4];
  const float* bih0  = (const float*)d_in[5];
  const float* bhh0  = (const float*)d_in[6];
  const float* Wih1  = (const float*)d_in[7];
  const float* Whh1  = (const float*)d_in[8];
  const float* bih1  = (const float*)d_in[9];
  const float* bhh1  = (const float*)d_in[10];
  const float* Wout  = (const float*)d_in[11];
  const float* bout  = (const float*)d_in[12];
  const float* trans = (const float*)d_in[13];

  float* ws = (float*)d_ws;
  float* X   = ws;
  float* H0  = ws + 262144;
  float* H1  = ws + 786432;
  float* LOG = ws + 1310720;

  // sentinel-init H0|H1: 0xFFFFFFFF == NaN, unreachable for computed h.
  // Must run every launch (harness re-poisons ws with 0xAA).
  hipMemsetAsync(H0, 0xFF, (size_t)1048576 * sizeof(float), stream);

  k_embed<<<kS, 128, 0, stream>>>(source, emb, X);
  k_rec<512><<<64, 512, 0, stream>>>(X, X, Wih0, Whh0, bih0, bhh0, H0);
  k_rec<1024><<<64, 512, 0, stream>>>(H0, H0 + 262144, Wih1, Whh1, bih1, bhh1, H1);
  k_logits<<<kS, 256, 0, stream>>>(H1, Wout, bout, LOG);
  k_viterbi<<<1, 256, 0, stream>>>(LOG, trans, (int*)d_out);
}

// Round 5
// 2045.216 us; speedup vs baseline: 1.2191x; 1.2191x over previous
//
#include <hip/hip_runtime.h>
#include <stdint.h>

constexpr int kS = 512;   // sequence length
constexpr int kB = 32;    // batch (only element 0 decoded)
constexpr int kH = 512;   // hidden
constexpr int kV = 64;    // tags

// ---------------------------------------------------------------------------
// ws layout (floats):
//   X    [512][512]     @ 0        (262144)
//   H0L  [2][512][512]  @ 262144   (524288)  XCD-local handoff copy (sc0/L2)
//   H0G  [2][512][512]  @ 786432   (524288)  agent/MALL copy (downstream reads)
//   H1L  [2][512][512]  @ 1310720  (524288)
//   H1G  [2][512][512]  @ 1835008  (524288)
//   LOG  [512][64]      @ 2359296  (32768)
// H0L..H1G memset to 0xFF each launch (sentinel = NaN, unreachable for |h|<1).
// ---------------------------------------------------------------------------

__device__ __forceinline__ float fast_sigmoid(float x) {
  return __builtin_amdgcn_rcpf(1.0f + __expf(-x));
}
__device__ __forceinline__ float fast_tanh(float x) {
  return 1.0f - 2.0f * __builtin_amdgcn_rcpf(1.0f + __expf(2.0f * x));
}
__device__ __forceinline__ float bcast(float v, int k) {
  return __uint_as_float(__builtin_amdgcn_readlane(__float_as_uint(v), k));
}
// L2-coherent (within one XCD) load/store: sc0 = bypass L1, serve from the
// XCD-shared L2. NOT cross-XCD coherent -- that's what the G-copy fallback is
// for. volatile + memory clobber stops hoisting/caching by the compiler.
__device__ __forceinline__ unsigned ld_l2(const unsigned* p) {
  unsigned r;
  asm volatile("global_load_dword %0, %1, off sc0\n\ts_waitcnt vmcnt(0)"
               : "=v"(r) : "v"(p) : "memory");
  return r;
}
__device__ __forceinline__ void st_l2(unsigned* p, unsigned v) {
  asm volatile("global_store_dword %0, %1, off sc0" :: "v"(p), "v"(v)
               : "memory");
}

__global__ __launch_bounds__(128) void k_embed(const int* __restrict__ src,
                                               const float* __restrict__ emb,
                                               float* __restrict__ X) {
  const int t = blockIdx.x;
  const int s = src[t * kB];  // batch 0 token
  const float4* e = (const float4*)(emb + (size_t)s * 512);
  float4* x = (float4*)(X + (size_t)t * 512);
  x[threadIdx.x] = e[threadIdx.x];
}

// Fused recurrence. Grid = 256 blocks, but only b%8 in {0,1} work (dir =
// b%8, wg = b>>3 in [0,32)): MI300-family round-robins blocks across the 8
// XCDs, so all 32 blocks of one direction heuristically share ONE XCD and
// hand off h through that XCD's L2 (~200 cyc) instead of the MALL coherence
// point (~900 cyc). Placement is a heuristic: producers dual-publish
// (sc0 -> local L2 copy HL, agent-scope -> MALL copy HG); consumers spin 4
// tries on HL then fall back to HG -- wrong placement costs time, never
// correctness. All 256 blocks are co-resident (1 block/CU), so spin-waiting
// is deadlock-free. wg owns h[wg*16..+16) -> 64 gate rows; lane l of each
// wave owns gate row l; wave wv owns k-slice [wv*64,+64) of Whh and
// [wv*KZ/8,+KZ/8) of Wih (weights in registers/AGPRs, loaded once).
template <int KZ>
__global__ __launch_bounds__(512, 1) void k_rec(
    const float* __restrict__ Z0,   // layer0: X; layer1: H0G fwd
    const float* __restrict__ Z1,   // layer1: H0G bwd (unused for KZ==512)
    const float* __restrict__ Wih,  // [2][2048][KZ]
    const float* __restrict__ Whh,  // [2][2048][512]
    const float* __restrict__ bih,  // [2][2048]
    const float* __restrict__ bhh,  // [2][2048]
    float* __restrict__ HL,         // [2][512][512] local-L2 handoff copy
    float* __restrict__ HG) {       // [2][512][512] MALL copy (downstream)
  constexpr int ZPW = KZ / 8;       // z k-slice per wave (64 or 128)
  __shared__ float part[64 * 9];    // [row][wave], stride 9: odd -> no 4-way
  const int b = blockIdx.x;
  const int xslot = b & 7;
  if (xslot > 1) return;            // workers only on XCD 0/1 (heuristic)
  const int dir = xslot, wg = b >> 3;
  const int tid = threadIdx.x;
  const int wv = tid >> 6, l = tid & 63;
  const float* WihB = Wih + (size_t)dir * 2048 * KZ;
  const float* WhhB = Whh + (size_t)dir * 2048 * 512;
  float* HbL = HL + (size_t)dir * kS * kH;
  float* HbG = HG + (size_t)dir * kS * kH;
  const int grow = (l >> 4) * 512 + wg * 16 + (l & 15);

  // --- one-time weight loads into registers ---
  float ww[64];
  {
    const float* wp = WhhB + (size_t)grow * 512 + wv * 64;
#pragma unroll
    for (int i = 0; i < 64; i += 4) {
      const float4 v = *(const float4*)(wp + i);
      ww[i] = v.x; ww[i + 1] = v.y; ww[i + 2] = v.z; ww[i + 3] = v.w;
    }
  }
  float zw[ZPW];
  {
    const float* zp = WihB + (size_t)grow * KZ + wv * ZPW;
#pragma unroll
    for (int i = 0; i < ZPW; i += 4) {
      const float4 v = *(const float4*)(zp + i);
      zw[i] = v.x; zw[i + 1] = v.y; zw[i + 2] = v.z; zw[i + 3] = v.w;
    }
  }
  float bias = 0.0f;
  if (wv == 0) bias = bih[dir * 2048 + grow] + bhh[dir * 2048 + grow];
  float cstate = 0.0f;  // live in wave 0, lanes < 16

  const float* zbase = (KZ == 512) ? Z0 : ((wv < 4) ? Z0 : Z1);
  const int zoff = (KZ == 512) ? tid : ((wv & 3) * 128 + l);

  const int t0 = dir ? (kS - 1) : 0;
  float zc0 = zbase[(size_t)t0 * 512 + zoff];
  float zc1 = (KZ == 1024) ? zbase[(size_t)t0 * 512 + zoff + 64] : 0.0f;

  for (int s = 0; s < kS; s++) {
    const int t = dir ? (kS - 1 - s) : s;
    int tn = dir ? (t - 1) : (t + 1);
    if (tn < 0) tn = 0;
    if (tn > kS - 1) tn = kS - 1;
    // next-step z prefetch (independent, hides under matvec/poll)
    const float zn0 = zbase[(size_t)tn * 512 + zoff];
    const float zn1 = (KZ == 1024) ? zbase[(size_t)tn * 512 + zoff + 64] : 0.0f;

    // --- input-gate matvec: independent of h, overlaps producer tail ---
    float a0 = 0.f, a1 = 0.f, a2 = 0.f, a3 = 0.f;
#pragma unroll
    for (int k = 0; k < 64; k += 4) {
      a0 += zw[k + 0] * bcast(zc0, k + 0);
      a1 += zw[k + 1] * bcast(zc0, k + 1);
      a2 += zw[k + 2] * bcast(zc0, k + 2);
      a3 += zw[k + 3] * bcast(zc0, k + 3);
    }
    if (KZ == 1024) {
#pragma unroll
      for (int k = 0; k < 64; k += 4) {
        a0 += zw[64 + k + 0] * bcast(zc1, k + 0);
        a1 += zw[64 + k + 1] * bcast(zc1, k + 1);
        a2 += zw[64 + k + 2] * bcast(zc1, k + 2);
        a3 += zw[64 + k + 3] * bcast(zc1, k + 3);
      }
    }

    // --- poll previous h: local-L2 fast path, MALL fallback ---
    float hreg = 0.0f;
    if (s > 0) {
      const int tp = dir ? (t + 1) : (t - 1);
      const unsigned* lp = (const unsigned*)(HbL + (size_t)tp * kH) + tid;
      const unsigned* gp = (const unsigned*)(HbG + (size_t)tp * kH) + tid;
      unsigned u = ld_l2(lp);
#pragma unroll 1
      for (int r = 0; r < 4; r++) {
        if (u != 0xFFFFFFFFu) break;
        u = ld_l2(lp);
      }
      while (u == 0xFFFFFFFFu)  // cross-XCD producer: coherent MALL path
        u = __hip_atomic_load(gp, __ATOMIC_RELAXED, __HIP_MEMORY_SCOPE_AGENT);
      hreg = __uint_as_float(u);
    }

    // --- recurrent matvec: readlane broadcast ---
#pragma unroll
    for (int k = 0; k < 64; k += 4) {
      a0 += ww[k + 0] * bcast(hreg, k + 0);
      a1 += ww[k + 1] * bcast(hreg, k + 1);
      a2 += ww[k + 2] * bcast(hreg, k + 2);
      a3 += ww[k + 3] * bcast(hreg, k + 3);
    }
    part[l * 9 + wv] = (a0 + a1) + (a2 + a3);
    __syncthreads();
    // waves 1..7 fall through to next step immediately; wave 0 does the cell.
    if (wv == 0) {
      float ssum = bias;
#pragma unroll
      for (int w = 0; w < 8; w++) ssum += part[l * 9 + w];
      const float sf = __shfl(ssum, (l + 16) & 63);
      const float sg = __shfl(ssum, (l + 32) & 63);
      const float so = __shfl(ssum, (l + 48) & 63);
      if (l < 16) {
        const float ig = fast_sigmoid(ssum);
        const float fg = fast_sigmoid(sf);
        const float og = fast_sigmoid(so);
        cstate = fg * cstate + ig * fast_tanh(sg);
        const float h = og * fast_tanh(cstate);
        const unsigned hv = __float_as_uint(h);
        unsigned* lq = (unsigned*)(HbL + (size_t)t * kH) + wg * 16 + l;
        unsigned* gq = (unsigned*)(HbG + (size_t)t * kH) + wg * 16 + l;
        st_l2(lq, hv);  // same-XCD consumers see this in shared L2
        __hip_atomic_store(gq, hv, __ATOMIC_RELAXED,
                           __HIP_MEMORY_SCOPE_AGENT);  // everyone else
      }
    }
    zc0 = zn0;
    zc1 = zn1;
  }
}

__global__ __launch_bounds__(256) void k_logits(const float* __restrict__ H1,
                                                const float* __restrict__ Wout,
                                                const float* __restrict__ bout,
                                                float* __restrict__ LOG) {
  __shared__ float hl[1024];
  const int t = blockIdx.x;
  const int tid = threadIdx.x;
  float4* hl4 = (float4*)hl;
  if (tid < 128)
    hl4[tid] = ((const float4*)(H1 + (size_t)t * kH))[tid];
  else
    hl4[tid] = ((const float4*)(H1 + (size_t)(kS + t) * kH))[tid - 128];
  __syncthreads();
  const int v = tid >> 2, q = tid & 3;
  const float4* w4 = (const float4*)(Wout + (size_t)v * 1024);
  float4 a = {0, 0, 0, 0};
#pragma unroll 8
  for (int j = 0; j < 64; j++) {
    const int idx = j * 4 + q;
    const float4 w = w4[idx];
    const float4 x = hl4[idx];
    a.x += w.x * x.x; a.y += w.y * x.y; a.z += w.z * x.z; a.w += w.w * x.w;
  }
  float acc = (a.x + a.y) + (a.z + a.w);
  acc += __shfl_xor(acc, 1);
  acc += __shfl_xor(acc, 2);
  if (q == 0) LOG[(size_t)t * kV + v] = acc + bout[v];
}

__global__ __launch_bounds__(256) void k_viterbi(const float* __restrict__ LOG,
                                                 const float* __restrict__ trans,
                                                 int* __restrict__ out) {
  __shared__ float delta[64];
  __shared__ float redS[4 * 64];
  __shared__ int redA[4 * 64];
  __shared__ unsigned char bp[511 * 64];
  const int tid = threadIdx.x;
  const int c = tid & 63, q = tid >> 6;
  if (tid < 64) delta[tid] = LOG[tid];
  __syncthreads();
  for (int t = 1; t < kS; t++) {
    float best = -1e30f;
    int bi = 0;
#pragma unroll 4
    for (int pp = 0; pp < 16; pp++) {
      const int p = q * 16 + pp;
      const float sc = delta[p] + trans[p * 64 + c];
      if (sc > best) { best = sc; bi = p; }  // strict > == first-max (numpy)
    }
    redS[q * 64 + c] = best;
    redA[q * 64 + c] = bi;
    __syncthreads();
    if (tid < 64) {
      float b = redS[c];
      int a = redA[c];
      for (int qq = 1; qq < 4; qq++) {
        const float v2 = redS[qq * 64 + c];
        if (v2 > b) { b = v2; a = redA[qq * 64 + c]; }
      }
      bp[(t - 1) * 64 + c] = (unsigned char)a;
      delta[c] = b + LOG[t * 64 + c];
    }
    __syncthreads();
  }
  if (tid == 0) {
    float b = delta[0];
    int a = 0;
    for (int i = 1; i < 64; i++)
      if (delta[i] > b) { b = delta[i]; a = i; }
    int idx = a;
    out[kS - 1] = idx;
    for (int t = kS - 2; t >= 0; t--) {
      idx = bp[t * 64 + idx];
      out[t] = idx;
    }
  }
}

extern "C" void kernel_launch(void* const* d_in, const int* in_sizes, int n_in,
                              void* d_out, int out_size, void* d_ws,
                              size_t ws_size, hipStream_t stream) {
  (void)in_sizes; (void)n_in; (void)out_size; (void)ws_size;
  const int* source  = (const int*)d_in[0];
  const float* emb   = (const float*)d_in[2];
  const float* Wih0  = (const float*)d_in[3];
  const float* Whh0  = (const float*)d_in[4];
  const float* bih0  = (const float*)d_in[5];
  const float* bhh0  = (const float*)d_in[6];
  const float* Wih1  = (const float*)d_in[7];
  const float* Whh1  = (const float*)d_in[8];
  const float* bih1  = (const float*)d_in[9];
  const float* bhh1  = (const float*)d_in[10];
  const float* Wout  = (const float*)d_in[11];
  const float* bout  = (const float*)d_in[12];
  const float* trans = (const float*)d_in[13];

  float* ws = (float*)d_ws;
  float* X   = ws;
  float* H0L = ws + 262144;
  float* H0G = ws + 786432;
  float* H1L = ws + 1310720;
  float* H1G = ws + 1835008;
  float* LOG = ws + 2359296;

  // sentinel-init all four handoff buffers (contiguous 8 MB): 0xFFFFFFFF is
  // NaN, unreachable for computed h. Must run every launch (0xAA re-poison).
  hipMemsetAsync(H0L, 0xFF, (size_t)4 * 524288 * sizeof(float), stream);

  k_embed<<<kS, 128, 0, stream>>>(source, emb, X);
  k_rec<512><<<256, 512, 0, stream>>>(X, X, Wih0, Whh0, bih0, bhh0, H0L, H0G);
  k_rec<1024><<<256, 512, 0, stream>>>(H0G, H0G + 262144, Wih1, Whh1, bih1,
                                       bhh1, H1L, H1G);
  k_logits<<<kS, 256, 0, stream>>>(H1G, Wout, bout, LOG);
  k_viterbi<<<1, 256, 0, stream>>>(LOG, trans, (int*)d_out);
}